// Round 12
// baseline (315.172 us; speedup 1.0000x reference)
//
#include <hip/hip_runtime.h>

typedef float f32x4 __attribute__((ext_vector_type(4)));
typedef short s16x8 __attribute__((ext_vector_type(8)));
typedef unsigned int u32x4 __attribute__((ext_vector_type(4)));
typedef unsigned char u8;
typedef unsigned short u16;
typedef unsigned int u32;
typedef unsigned long long u64;

#define NPOS 4096
#define CCH  256
#define MTOT 16384
#define PBYTES ((size_t)NPOS * NPOS * 2)   // one batch E, bf16 = 32 MB

// ---- ws layout (bytes) ---- (identical to round 8)
#define SZ_F8   ((size_t)MTOT * 256)
#define O_F8    ((size_t)0)                        // [4] fp8 [16384][256]
#define O_WT    (O_F8   + 4 * SZ_F8)               // bf16 [5][256][256]
#define O_XW3T  (O_WT   + (size_t)5*256*256*2)     // bf16 [4][256][4096] (UNscaled)
#define O_ZX    (O_XW3T + (size_t)MTOT*256*2)      // f32 [8][16384]
#define O_ZG    (O_ZX   + (size_t)8*MTOT*4)
#define O_ID    (O_ZG   + (size_t)8*MTOT*4)        // f32 [16384]
#define O_Z2    (O_ID   + (size_t)MTOT*4)          // f32 [64][16384]
#define O_IZ2   (O_Z2   + (size_t)64*MTOT*4)       // f32 [16384]
#define O_P     (O_IZ2  + (size_t)MTOT*4)          // bf16 E (never overwritten)

__device__ __forceinline__ u16 f2bf(float f) {
    u32 u = __builtin_bit_cast(u32, f);
    u32 r = (u + 0x7FFFu + ((u >> 16) & 1u)) >> 16;
    return (u16)r;
}
__device__ __forceinline__ float bf2f(u16 h) {
    u32 u = ((u32)h) << 16;
    return __builtin_bit_cast(float, u);
}
__device__ __forceinline__ u32 pk2(float a, float b) {
    return (u32)f2bf(a) | ((u32)f2bf(b) << 16);
}
__device__ __forceinline__ f32x4 mfma_bf16(s16x8 a, s16x8 b, f32x4 c) {
    return __builtin_amdgcn_mfma_f32_16x16x32_bf16(a, b, c, 0, 0, 0);
}
__device__ __forceinline__ f32x4 mfma_fp8(long a, long b, f32x4 c) {
    return __builtin_amdgcn_mfma_f32_16x16x32_fp8_fp8(a, b, c, 0, 0, 0);
}
__device__ __forceinline__ int xcd_swz(int bid, int nwg) {
    return (bid & 7) * (nwg >> 3) + (bid >> 3);
}
__device__ __forceinline__ u32x4 ntld(const void* p) {
    return __builtin_nontemporal_load((const u32x4*)p);
}
__device__ __forceinline__ void ntst(void* p, u32x4 v) {
    __builtin_nontemporal_store(v, (u32x4*)p);
}

// ---------------------------------------------------------------------------
__global__ __launch_bounds__(256) void prep_w(
    const float* __restrict__ W0, const float* __restrict__ W1,
    const float* __restrict__ W2, const float* __restrict__ W3,
    const float* __restrict__ W4, u32* __restrict__ wT)
{
    const int p = blockIdx.x, kq = blockIdx.y, n = threadIdx.x;
    const float* W = (p==0)?W0:(p==1)?W1:(p==2)?W2:(p==3)?W3:W4;
#pragma unroll 4
    for (int kk = 0; kk < 32; ++kk) {
        int k = kq*64 + kk*2;
        float v0 = W[k*256 + n];
        float v1 = W[(k+1)*256 + n];
        wT[(p*65536 + n*256 + k) >> 1] = pk2(v0, v1);
    }
}

// ---------------------------------------------------------------------------
// proj: 5 projections with bf16 MFMA. grid (128, 2), block 256 (4 waves 2x2).
// ---------------------------------------------------------------------------
__global__ __launch_bounds__(256) void proj_kernel(
    const float* __restrict__ x, const float* __restrict__ g,
    const float* __restrict__ bb0, const float* __restrict__ bb1,
    const float* __restrict__ bb2, const float* __restrict__ bb3,
    const float* __restrict__ bb4,
    const u16* __restrict__ wT, u8* __restrict__ f8, u8* __restrict__ xw3T)
{
    const int branch = blockIdx.y;
    const int m0 = blockIdx.x * 128;
    const float* A = branch ? g : x;
    __shared__ u8 sA[128*512];
    __shared__ u8 sC[128*512];
    const int t = threadIdx.x;
    const int l = t & 63, lr = l & 15, lg = l >> 4;
    const int wv = t >> 6, wm = wv >> 1, wn = wv & 1;

    {
        const int m = t >> 1, h = t & 1;
        const float* src = &A[(size_t)(m0 + m) * 256 + h * 128];
        const u32 dbase = m * 512;
#pragma unroll
        for (int c = 0; c < 16; ++c) {
            float4 a = *(const float4*)(src + c*8);
            float4 b = *(const float4*)(src + c*8 + 4);
            u32 pk[4] = { pk2(a.x, a.y), pk2(a.z, a.w), pk2(b.x, b.y), pk2(b.z, b.w) };
            int kbyte = h*256 + c*16;
            *(uint4*)&sA[dbase + (kbyte ^ ((m & 7) << 4))] = *(uint4*)pk;
        }
    }
    __syncthreads();

    const int np = branch ? 2 : 3;
    for (int pp = 0; pp < np; ++pp) {
        const int p = branch ? 3 + pp : pp;
        const float* bias = (p==0)?bb0:(p==1)?bb1:(p==2)?bb2:(p==3)?bb3:bb4;
        f32x4 acc[4][8];
#pragma unroll
        for (int i = 0; i < 4; ++i)
#pragma unroll
            for (int j = 0; j < 8; ++j) acc[i][j] = (f32x4){0.f,0.f,0.f,0.f};

#pragma unroll
        for (int ks = 0; ks < 8; ++ks) {
            s16x8 af[4];
#pragma unroll
            for (int Mt = 0; Mt < 4; ++Mt) {
                int m = wm*64 + Mt*16 + lr;
                af[Mt] = *(const s16x8*)&sA[m*512 + ((ks*64 + lg*16) ^ ((m & 7) << 4))];
            }
#pragma unroll
            for (int Nt = 0; Nt < 8; ++Nt) {
                int n = wn*128 + Nt*16 + lr;
                s16x8 bf = *(const s16x8*)&wT[p*65536 + n*256 + ks*32 + lg*8];
#pragma unroll
                for (int Mt = 0; Mt < 4; ++Mt)
                    acc[Mt][Nt] = mfma_bf16(af[Mt], bf, acc[Mt][Nt]);
            }
        }
#pragma unroll
        for (int Nt = 0; Nt < 8; ++Nt) {
            float bv = bias[wn*128 + Nt*16 + lr];
#pragma unroll
            for (int Mt = 0; Mt < 4; ++Mt)
#pragma unroll
                for (int q = 0; q < 4; ++q) acc[Mt][Nt][q] += bv;
        }

        if (p == 2) {
#pragma unroll
            for (int Mt = 0; Mt < 4; ++Mt)
#pragma unroll
                for (int Nt = 0; Nt < 8; ++Nt) {
                    int n = wn*128 + Nt*16 + lr;
                    int mrow = m0 + wm*64 + Mt*16 + lg*4;
                    int bb = mrow >> 12, pos = mrow & 4095;
                    uint2 val;
                    val.x = pk2(acc[Mt][Nt][0], acc[Mt][Nt][1]);
                    val.y = pk2(acc[Mt][Nt][2], acc[Mt][Nt][3]);
                    *(uint2*)(xw3T + ((size_t)(bb*256 + n)*4096 + pos)*2) = val;
                }
        } else {
            const int fi = (p < 2) ? p : p - 1;
#pragma unroll
            for (int Mt = 0; Mt < 4; ++Mt)
#pragma unroll
                for (int Nt = 0; Nt < 8; ++Nt) {
                    int n = wn*128 + Nt*16 + lr;
#pragma unroll
                    for (int q = 0; q < 4; ++q) {
                        int m = wm*64 + Mt*16 + lg*4 + q;
                        *(u16*)&sC[m*512 + ((n*2) ^ ((m & 7) << 4))] = f2bf(acc[Mt][Nt][q]);
                    }
                }
            __syncthreads();
            {
                const int m = t >> 1, h = t & 1;
                u8* dst = f8 + (size_t)fi * SZ_F8 + (size_t)(m0 + m)*256 + h*128;
#pragma unroll
                for (int c = 0; c < 16; ++c) {
                    uint4 v = *(const uint4*)&sC[m*512 + ((h*256 + c*16) ^ ((m & 7) << 4))];
                    float fv[8] = { bf2f((u16)(v.x & 0xffff)), bf2f((u16)(v.x >> 16)),
                                    bf2f((u16)(v.y & 0xffff)), bf2f((u16)(v.y >> 16)),
                                    bf2f((u16)(v.z & 0xffff)), bf2f((u16)(v.z >> 16)),
                                    bf2f((u16)(v.w & 0xffff)), bf2f((u16)(v.w >> 16)) };
                    u32 o0 = 0, o1 = 0;
                    o0 = __builtin_amdgcn_cvt_pk_fp8_f32(fv[0], fv[1], o0, false);
                    o0 = __builtin_amdgcn_cvt_pk_fp8_f32(fv[2], fv[3], o0, true);
                    o1 = __builtin_amdgcn_cvt_pk_fp8_f32(fv[4], fv[5], o1, false);
                    o1 = __builtin_amdgcn_cvt_pk_fp8_f32(fv[6], fv[7], o1, true);
                    uint2 ov; ov.x = o0; ov.y = o1;
                    *(uint2*)(dst + c*8) = ov;
                }
            }
            __syncthreads();
        }
    }
}

// ---------------------------------------------------------------------------
// score: EXACT round-8 structure (proven 89us). Sx,Sg fp8 MFMA; writes
// E=exp(Sx)*exp(Sg) bf16 (nt) + Zx/Zg partials. grid 256*nb, 256 thr.
// ---------------------------------------------------------------------------
__global__ __launch_bounds__(256, 3) void score_kernel(
    const u8* __restrict__ f8, float* __restrict__ ZxP, float* __restrict__ ZgP,
    u8* __restrict__ PT, int bbase, int big)
{
    const int sid = xcd_swz(blockIdx.x, gridDim.x);
    const int bz = sid >> 8, rem = sid & 255;
    const int batch = bbase + bz;
    const int iblk = rem & 31, js = rem >> 5;
    const int i0 = iblk * 128;
    const int t = threadIdx.x, l = t & 63, lr = l & 15, lg = l >> 4, w = t >> 6;
    const u8* Ax = f8 + SZ_F8*1 + ((size_t)(batch*NPOS + i0 + w*32))*256;
    const u8* Ag = f8 + SZ_F8*3 + ((size_t)(batch*NPOS + i0 + w*32))*256;
    const u8* Bx = f8 + SZ_F8*0 + ((size_t)(batch*NPOS))*256;
    const u8* Bg = f8 + SZ_F8*2 + ((size_t)(batch*NPOS))*256;
    u8* PTb = PT + (big ? (size_t)bz * PBYTES : 0);

    long ax[2][8], ag[2][8];
#pragma unroll
    for (int Mt = 0; Mt < 2; ++Mt)
#pragma unroll
        for (int ks = 0; ks < 8; ++ks) {
            ax[Mt][ks] = *(const long*)&Ax[(Mt*16 + lr)*256 + ks*32 + lg*8];
            ag[Mt][ks] = *(const long*)&Ag[(Mt*16 + lr)*256 + ks*32 + lg*8];
        }

    float zx[2][4], zg[2][4];
#pragma unroll
    for (int Mt = 0; Mt < 2; ++Mt)
#pragma unroll
        for (int q = 0; q < 4; ++q) { zx[Mt][q] = 0.f; zg[Mt][q] = 0.f; }

    __shared__ __attribute__((aligned(16))) u8 sb[16384];
    __shared__ __attribute__((aligned(16))) u8 pb[8192];   // [32 j][128 i] bf16
    for (int jc = 0; jc < 16; ++jc) {
        const int j0 = js*512 + jc*32;
#pragma unroll
        for (int rep = 0; rep < 4; ++rep) {
            int s = rep*256 + t;
            int br = s >> 9, s2 = s & 511;
            int jr = s2 >> 4, kb = (s2 & 15) << 4;
            const u8* src = (br ? Bg : Bx) + (size_t)(j0 + jr)*256 + kb;
            uint4 v = *(const uint4*)src;
            int a0 = br*8192 + jr*256 + (kb ^ ((jr & 15) << 3));
            *(u64*)&sb[a0]     = ((u64)v.y << 32) | v.x;
            *(u64*)&sb[a0 ^ 8] = ((u64)v.w << 32) | v.z;
        }
        __syncthreads();
        f32x4 cx[2][2], cg[2][2];
#pragma unroll
        for (int Mt = 0; Mt < 2; ++Mt)
#pragma unroll
            for (int jt = 0; jt < 2; ++jt) { cx[Mt][jt] = (f32x4){0,0,0,0}; cg[Mt][jt] = (f32x4){0,0,0,0}; }
#pragma unroll
        for (int ks = 0; ks < 8; ++ks)
#pragma unroll
            for (int jt = 0; jt < 2; ++jt) {
                int jrow = jt*16 + lr;
                int off = jrow*256 + ((ks*32 + lg*8) ^ ((jrow & 15) << 3));
                long bxv = *(const long*)&sb[off];
                long bgv = *(const long*)&sb[8192 + off];
#pragma unroll
                for (int Mt = 0; Mt < 2; ++Mt) {
                    cx[Mt][jt] = mfma_fp8(ax[Mt][ks], bxv, cx[Mt][jt]);
                    cg[Mt][jt] = mfma_fp8(ag[Mt][ks], bgv, cg[Mt][jt]);
                }
            }
        // E = exp(Sx)*exp(Sg) -> LDS bounce; Zx,Zg accumulate
#pragma unroll
        for (int Mt = 0; Mt < 2; ++Mt)
#pragma unroll
            for (int jt = 0; jt < 2; ++jt) {
                int jl = jt*16 + lr;
                float e[4];
#pragma unroll
                for (int q = 0; q < 4; ++q) {
                    float exv = __expf(cx[Mt][jt][q]);
                    float egv = __expf(cg[Mt][jt][q]);
                    zx[Mt][q] += exv;
                    zg[Mt][q] += egv;
                    e[q] = exv * egv;
                }
                u64 pk = (u64)pk2(e[0], e[1]) | ((u64)pk2(e[2], e[3]) << 32);
                int ioff = w*64 + Mt*32 + lg*8;
                *(u64*)&pb[jl*256 + (ioff ^ ((jl & 15) << 3))] = pk;
            }
        __syncthreads();
        { // coalesced E store (nt): 32 rows x 256 B
            const int row = t >> 3, seg = t & 7;
            const int swz = (row & 15) << 3;
            u8* dst = PTb + (size_t)(j0 + row)*8192 + (size_t)i0*2 + seg*32;
#pragma unroll
            for (int h = 0; h < 2; ++h) {
                int a0 = row*256 + ((seg*32 + h*16) ^ swz);
                u64 lo = *(const u64*)&pb[a0];
                u64 hi = *(const u64*)&pb[a0 ^ 8];
                u32x4 o;
                o[0] = (u32)lo; o[1] = (u32)(lo >> 32);
                o[2] = (u32)hi; o[3] = (u32)(hi >> 32);
                ntst(dst + h*16, o);
            }
        }
        __syncthreads();
    }
#pragma unroll
    for (int Mt = 0; Mt < 2; ++Mt)
#pragma unroll
        for (int q = 0; q < 4; ++q)
#pragma unroll
            for (int o = 1; o < 16; o <<= 1) {
                zx[Mt][q] += __shfl_xor(zx[Mt][q], o, 64);
                zg[Mt][q] += __shfl_xor(zg[Mt][q], o, 64);
            }
    if (lr == 0) {
#pragma unroll
        for (int Mt = 0; Mt < 2; ++Mt)
#pragma unroll
            for (int q = 0; q < 4; ++q) {
                int gi = batch*NPOS + i0 + w*32 + Mt*16 + lg*4 + q;
                ZxP[js*MTOT + gi] = zx[Mt][q];
                ZgP[js*MTOT + gi] = zg[Mt][q];
            }
    }
}

// ---------------------------------------------------------------------------
__global__ __launch_bounds__(256) void merge_d(
    const float* __restrict__ ZxP, const float* __restrict__ ZgP,
    float* __restrict__ iD, int bbase)
{
    int gi = bbase*NPOS + blockIdx.x*256 + threadIdx.x;
    float zx = 0.f, zg = 0.f;
#pragma unroll
    for (int js = 0; js < 8; ++js) { zx += ZxP[js*MTOT + gi]; zg += ZgP[js*MTOT + gi]; }
    iD[gi] = 1.0f / (zx * zg);
}

// ---------------------------------------------------------------------------
// zpass: READ-ONLY sweep of E -> z2 partials (no P write-back; pv computes
// exp inline). 1D grid 128*nb = (ih 2, js 64, batch), 256 thr.
// ---------------------------------------------------------------------------
__global__ __launch_bounds__(256) void zpass_kernel(
    const u8* __restrict__ PT, const float* __restrict__ iD,
    float* __restrict__ z2P, int bbase, int big)
{
    const int sid = xcd_swz(blockIdx.x, gridDim.x);
    const int bz = sid >> 7, r = sid & 127;
    const int ih = r >> 6, js = r & 63;
    const int batch = bbase + bz;
    const u8* base = PT + (big ? (size_t)bz * PBYTES : 0) + (size_t)(js*64)*8192;
    const int i = ih*2048 + threadIdx.x*8;
    f32x4 d0 = *(const f32x4*)&iD[batch*NPOS + i];
    f32x4 d1 = *(const f32x4*)&iD[batch*NPOS + i + 4];
    f32x4 z0 = (f32x4){0,0,0,0}, z1 = (f32x4){0,0,0,0};
#pragma unroll 4
    for (int jr = 0; jr < 64; ++jr) {
        u32x4 v = ntld(base + (size_t)jr*8192 + (size_t)i*2);
        z0[0] += __expf(bf2f((u16)(v[0] & 0xffff)) * d0[0]);
        z0[1] += __expf(bf2f((u16)(v[0] >> 16))    * d0[1]);
        z0[2] += __expf(bf2f((u16)(v[1] & 0xffff)) * d0[2]);
        z0[3] += __expf(bf2f((u16)(v[1] >> 16))    * d0[3]);
        z1[0] += __expf(bf2f((u16)(v[2] & 0xffff)) * d1[0]);
        z1[1] += __expf(bf2f((u16)(v[2] >> 16))    * d1[1]);
        z1[2] += __expf(bf2f((u16)(v[3] & 0xffff)) * d1[2]);
        z1[3] += __expf(bf2f((u16)(v[3] >> 16))    * d1[3]);
    }
    float* dst = z2P + (size_t)js*MTOT + batch*NPOS + i;
    *(f32x4*)dst = z0;
    *(f32x4*)(dst + 4) = z1;
}

// ---------------------------------------------------------------------------
__global__ __launch_bounds__(256) void prep_iz2(
    const float* __restrict__ z2P, float* __restrict__ iZ2, int bbase)
{
    int gi = bbase*NPOS + blockIdx.x*256 + threadIdx.x;
    float s = 0.f;
#pragma unroll 8
    for (int js = 0; js < 64; ++js) s += z2P[js*MTOT + gi];
    iZ2[gi] = 1.0f / s;
}

// ---------------------------------------------------------------------------
// pv: out = x + P @ (xw3T*iZ2)^T with P = exp(E*iD) computed INLINE during
// A-staging, iZ2 applied inline during B-staging. Round-8 pv skeleton:
// double-buffered reg staging, one barrier per K-step, tile 64j x 64c,
// grid 256*nb, c fast (L2 sharing of E panels).
// ---------------------------------------------------------------------------
__global__ __launch_bounds__(256, 4) void pv_kernel(
    const u8* __restrict__ PT, const u8* __restrict__ xw3T,
    const float* __restrict__ iD, const float* __restrict__ iZ2,
    const float* __restrict__ x, float* __restrict__ out, int bbase, int big)
{
    const int sid = xcd_swz(blockIdx.x, gridDim.x);
    const int bz = sid >> 8, rem = sid & 255;
    const int batch = bbase + bz;
    const int j0 = (rem >> 2) * 64, c0 = (rem & 3) * 64;
    const u8* PTb = PT + (big ? (size_t)bz * PBYTES : 0);
    const u8* xw3Tb = xw3T + (size_t)batch * 256 * 4096 * 2;
    const float* iDb = iD + batch*NPOS;
    const float* iZb = iZ2 + batch*NPOS;
    __shared__ __attribute__((aligned(16))) u8 sA[2][8192];   // bf16 [64 j][64 k]
    __shared__ __attribute__((aligned(16))) u8 sB[2][8192];   // bf16 [64 c][64 k]
    const int t = threadIdx.x, l = t & 63, lr = l & 15, lg = l >> 4;
    const int wv = t >> 6, wm = wv >> 1, wn = wv & 1;
    const int srow = t >> 3, sseg = t & 7;

    f32x4 acc[2][2];
#pragma unroll
    for (int Mt = 0; Mt < 2; ++Mt)
#pragma unroll
        for (int Nt = 0; Nt < 2; ++Nt) acc[Mt][Nt] = (f32x4){0,0,0,0};

    u32x4 ra[2], rb[2];
    f32x4 rd0, rd1, rz0, rz1;
    {   // prologue: load tile 0 (+ per-k scale vectors)
#pragma unroll
        for (int rp = 0; rp < 2; ++rp) {
            int row = rp*32 + srow;
            ra[rp] = *(const u32x4*)(PTb + (size_t)(j0 + row)*8192 + (size_t)(sseg*8)*2);
            rb[rp] = *(const u32x4*)(xw3Tb + ((size_t)(c0 + row)*4096 + sseg*8)*2);
        }
        rd0 = *(const f32x4*)&iDb[sseg*8];
        rd1 = *(const f32x4*)&iDb[sseg*8 + 4];
        rz0 = *(const f32x4*)&iZb[sseg*8];
        rz1 = *(const f32x4*)&iZb[sseg*8 + 4];
    }
    for (int kt = 0; kt < 64; ++kt) {
        const int cur = kt & 1;
        // transform staged regs -> LDS[cur]
#pragma unroll
        for (int rp = 0; rp < 2; ++rp) {
            int row = rp*32 + srow;
            int ad = row*128 + ((sseg*16) ^ ((row & 7) << 4));
            u32x4 ea = ra[rp];
            u32x4 oa;
            oa[0] = pk2(__expf(bf2f((u16)(ea[0] & 0xffff))*rd0[0]), __expf(bf2f((u16)(ea[0] >> 16))*rd0[1]));
            oa[1] = pk2(__expf(bf2f((u16)(ea[1] & 0xffff))*rd0[2]), __expf(bf2f((u16)(ea[1] >> 16))*rd0[3]));
            oa[2] = pk2(__expf(bf2f((u16)(ea[2] & 0xffff))*rd1[0]), __expf(bf2f((u16)(ea[2] >> 16))*rd1[1]));
            oa[3] = pk2(__expf(bf2f((u16)(ea[3] & 0xffff))*rd1[2]), __expf(bf2f((u16)(ea[3] >> 16))*rd1[3]));
            *(u32x4*)&sA[cur][ad] = oa;
            u32x4 eb = rb[rp];
            u32x4 ob;
            ob[0] = pk2(bf2f((u16)(eb[0] & 0xffff))*rz0[0], bf2f((u16)(eb[0] >> 16))*rz0[1]);
            ob[1] = pk2(bf2f((u16)(eb[1] & 0xffff))*rz0[2], bf2f((u16)(eb[1] >> 16))*rz0[3]);
            ob[2] = pk2(bf2f((u16)(eb[2] & 0xffff))*rz1[0], bf2f((u16)(eb[2] >> 16))*rz1[1]);
            ob[3] = pk2(bf2f((u16)(eb[3] & 0xffff))*rz1[2], bf2f((u16)(eb[3] >> 16))*rz1[3]);
            *(u32x4*)&sB[cur][ad] = ob;
        }
        __syncthreads();
        if (kt < 63) {   // issue next tile's loads; latency hides under MFMA
            const int k0 = (kt + 1) * 64;
            const int ib = k0 + sseg*8;
#pragma unroll
            for (int rp = 0; rp < 2; ++rp) {
                int row = rp*32 + srow;
                ra[rp] = *(const u32x4*)(PTb + (size_t)(j0 + row)*8192 + (size_t)ib*2);
                rb[rp] = *(const u32x4*)(xw3Tb + ((size_t)(c0 + row)*4096 + ib)*2);
            }
            rd0 = *(const f32x4*)&iDb[ib];
            rd1 = *(const f32x4*)&iDb[ib + 4];
            rz0 = *(const f32x4*)&iZb[ib];
            rz1 = *(const f32x4*)&iZb[ib + 4];
        }
#pragma unroll
        for (int ks = 0; ks < 2; ++ks) {
            s16x8 af[2], bf[2];
#pragma unroll
            for (int Mt = 0; Mt < 2; ++Mt) {
                int row = wm*32 + Mt*16 + lr;
                af[Mt] = *(const s16x8*)&sA[cur][row*128 + ((ks*64 + lg*16) ^ ((row & 7) << 4))];
            }
#pragma unroll
            for (int Nt = 0; Nt < 2; ++Nt) {
                int row = wn*32 + Nt*16 + lr;
                bf[Nt] = *(const s16x8*)&sB[cur][row*128 + ((ks*64 + lg*16) ^ ((row & 7) << 4))];
            }
#pragma unroll
            for (int Mt = 0; Mt < 2; ++Mt)
#pragma unroll
                for (int Nt = 0; Nt < 2; ++Nt)
                    acc[Mt][Nt] = mfma_bf16(af[Mt], bf[Nt], acc[Mt][Nt]);
        }
    }
#pragma unroll
    for (int Mt = 0; Mt < 2; ++Mt)
#pragma unroll
        for (int Nt = 0; Nt < 2; ++Nt)
#pragma unroll
            for (int q = 0; q < 4; ++q) {
                int j = j0 + wm*32 + Mt*16 + lg*4 + q;
                int c = c0 + wn*32 + Nt*16 + lr;
                size_t idx = ((size_t)(batch*NPOS + j))*256 + c;
                out[idx] = x[idx] + acc[Mt][Nt][q];
            }
}

// ---------------------------------------------------------------------------
extern "C" void kernel_launch(void* const* d_in, const int* in_sizes, int n_in,
                              void* d_out, int out_size, void* d_ws, size_t ws_size,
                              hipStream_t stream)
{
    const float* x = (const float*)d_in[0];
    const float* g = (const float*)d_in[1];
    const float* W[5]  = {(const float*)d_in[2], (const float*)d_in[4], (const float*)d_in[6],
                          (const float*)d_in[8], (const float*)d_in[10]};
    const float* Bi[5] = {(const float*)d_in[3], (const float*)d_in[5], (const float*)d_in[7],
                          (const float*)d_in[9], (const float*)d_in[11]};
    char* ws = (char*)d_ws;
    u8*  f8   = (u8*)(ws + O_F8);
    u16* wT   = (u16*)(ws + O_WT);
    u8*  xw3T = (u8*)(ws + O_XW3T);
    float* ZxP = (float*)(ws + O_ZX);
    float* ZgP = (float*)(ws + O_ZG);
    float* iD  = (float*)(ws + O_ID);
    float* z2P = (float*)(ws + O_Z2);
    float* iZ2 = (float*)(ws + O_IZ2);
    u8*  PT   = (u8*)(ws + O_P);
    float* out = (float*)d_out;

    const int big = (ws_size >= O_P + 4 * PBYTES) ? 1 : 0;

    prep_w<<<dim3(5,4), 256, 0, stream>>>(W[0], W[1], W[2], W[3], W[4], (u32*)wT);
    proj_kernel<<<dim3(128,2), 256, 0, stream>>>(x, g, Bi[0], Bi[1], Bi[2], Bi[3], Bi[4],
                                                 wT, f8, xw3T);
    if (big) {
        score_kernel<<<1024, 256, 0, stream>>>(f8, ZxP, ZgP, PT, 0, 1);
        merge_d<<<64, 256, 0, stream>>>(ZxP, ZgP, iD, 0);
        zpass_kernel<<<512, 256, 0, stream>>>(PT, iD, z2P, 0, 1);
        prep_iz2<<<64, 256, 0, stream>>>(z2P, iZ2, 0);
        pv_kernel<<<1024, 256, 0, stream>>>(PT, xw3T, iD, iZ2, x, out, 0, 1);
    } else {
        for (int b = 0; b < 4; ++b) {
            score_kernel<<<256, 256, 0, stream>>>(f8, ZxP, ZgP, PT, b, 0);
            merge_d<<<16, 256, 0, stream>>>(ZxP, ZgP, iD, b);
            zpass_kernel<<<128, 256, 0, stream>>>(PT, iD, z2P, b, 0);
            prep_iz2<<<16, 256, 0, stream>>>(z2P, iZ2, b);
            pv_kernel<<<256, 256, 0, stream>>>(PT, xw3T, iD, iZ2, x, out, b, 0);
        }
    }
}

// Round 13
// 290.102 us; speedup vs baseline: 1.0864x; 1.0864x over previous
//
#include <hip/hip_runtime.h>

typedef float f32x4 __attribute__((ext_vector_type(4)));
typedef short s16x8 __attribute__((ext_vector_type(8)));
typedef unsigned int u32x4 __attribute__((ext_vector_type(4)));
typedef unsigned char u8;
typedef unsigned short u16;
typedef unsigned int u32;
typedef unsigned long long u64;

#define NPOS 4096
#define CCH  256
#define MTOT 16384
#define PBYTES ((size_t)NPOS * NPOS * 2)   // one batch E/P, bf16 = 32 MB

// ---- ws layout (bytes) ----
#define SZ_F8   ((size_t)MTOT * 256)
#define O_F8    ((size_t)0)                        // [4] fp8 [16384][256]
#define O_WT    (O_F8   + 4 * SZ_F8)               // bf16 [5][256][256]
#define O_XW3T  (O_WT   + (size_t)5*256*256*2)     // bf16 [4][256][4096] (scaled in place by iZ2)
#define O_ZX    (O_XW3T + (size_t)MTOT*256*2)      // f32 [8][16384]
#define O_ZG    (O_ZX   + (size_t)8*MTOT*4)
#define O_ID    (O_ZG   + (size_t)8*MTOT*4)        // f32 [16384]
#define O_Z2    (O_ID   + (size_t)MTOT*4)          // f32 [64][16384]
#define O_IZ2   (O_Z2   + (size_t)64*MTOT*4)       // f32 [16384]
#define O_P     (O_IZ2  + (size_t)MTOT*4)          // bf16 E->P in place

__device__ __forceinline__ u16 f2bf(float f) {
    u32 u = __builtin_bit_cast(u32, f);
    u32 r = (u + 0x7FFFu + ((u >> 16) & 1u)) >> 16;
    return (u16)r;
}
__device__ __forceinline__ float bf2f(u16 h) {
    u32 u = ((u32)h) << 16;
    return __builtin_bit_cast(float, u);
}
__device__ __forceinline__ u32 pk2(float a, float b) {
    return (u32)f2bf(a) | ((u32)f2bf(b) << 16);
}
__device__ __forceinline__ f32x4 mfma_bf16(s16x8 a, s16x8 b, f32x4 c) {
    return __builtin_amdgcn_mfma_f32_16x16x32_bf16(a, b, c, 0, 0, 0);
}
__device__ __forceinline__ f32x4 mfma_fp8(long a, long b, f32x4 c) {
    return __builtin_amdgcn_mfma_f32_16x16x32_fp8_fp8(a, b, c, 0, 0, 0);
}
__device__ __forceinline__ int xcd_swz(int bid, int nwg) {
    return (bid & 7) * (nwg >> 3) + (bid >> 3);
}
__device__ __forceinline__ u32x4 ntld(const void* p) {
    return __builtin_nontemporal_load((const u32x4*)p);
}
__device__ __forceinline__ void ntst(void* p, u32x4 v) {
    __builtin_nontemporal_store(v, (u32x4*)p);
}

// ---------------------------------------------------------------------------
__global__ __launch_bounds__(256) void prep_w(
    const float* __restrict__ W0, const float* __restrict__ W1,
    const float* __restrict__ W2, const float* __restrict__ W3,
    const float* __restrict__ W4, u32* __restrict__ wT)
{
    const int p = blockIdx.x, kq = blockIdx.y, n = threadIdx.x;
    const float* W = (p==0)?W0:(p==1)?W1:(p==2)?W2:(p==3)?W3:W4;
#pragma unroll 4
    for (int kk = 0; kk < 32; ++kk) {
        int k = kq*64 + kk*2;
        float v0 = W[k*256 + n];
        float v1 = W[(k+1)*256 + n];
        wT[(p*65536 + n*256 + k) >> 1] = pk2(v0, v1);
    }
}

// ---------------------------------------------------------------------------
// proj: 5 projections with bf16 MFMA. grid (128, 2), block 256 (4 waves 2x2).
// ---------------------------------------------------------------------------
__global__ __launch_bounds__(256) void proj_kernel(
    const float* __restrict__ x, const float* __restrict__ g,
    const float* __restrict__ bb0, const float* __restrict__ bb1,
    const float* __restrict__ bb2, const float* __restrict__ bb3,
    const float* __restrict__ bb4,
    const u16* __restrict__ wT, u8* __restrict__ f8, u8* __restrict__ xw3T)
{
    const int branch = blockIdx.y;
    const int m0 = blockIdx.x * 128;
    const float* A = branch ? g : x;
    __shared__ u8 sA[128*512];
    __shared__ u8 sC[128*512];
    const int t = threadIdx.x;
    const int l = t & 63, lr = l & 15, lg = l >> 4;
    const int wv = t >> 6, wm = wv >> 1, wn = wv & 1;

    {
        const int m = t >> 1, h = t & 1;
        const float* src = &A[(size_t)(m0 + m) * 256 + h * 128];
        const u32 dbase = m * 512;
#pragma unroll
        for (int c = 0; c < 16; ++c) {
            float4 a = *(const float4*)(src + c*8);
            float4 b = *(const float4*)(src + c*8 + 4);
            u32 pk[4] = { pk2(a.x, a.y), pk2(a.z, a.w), pk2(b.x, b.y), pk2(b.z, b.w) };
            int kbyte = h*256 + c*16;
            *(uint4*)&sA[dbase + (kbyte ^ ((m & 7) << 4))] = *(uint4*)pk;
        }
    }
    __syncthreads();

    const int np = branch ? 2 : 3;
    for (int pp = 0; pp < np; ++pp) {
        const int p = branch ? 3 + pp : pp;
        const float* bias = (p==0)?bb0:(p==1)?bb1:(p==2)?bb2:(p==3)?bb3:bb4;
        f32x4 acc[4][8];
#pragma unroll
        for (int i = 0; i < 4; ++i)
#pragma unroll
            for (int j = 0; j < 8; ++j) acc[i][j] = (f32x4){0.f,0.f,0.f,0.f};

#pragma unroll
        for (int ks = 0; ks < 8; ++ks) {
            s16x8 af[4];
#pragma unroll
            for (int Mt = 0; Mt < 4; ++Mt) {
                int m = wm*64 + Mt*16 + lr;
                af[Mt] = *(const s16x8*)&sA[m*512 + ((ks*64 + lg*16) ^ ((m & 7) << 4))];
            }
#pragma unroll
            for (int Nt = 0; Nt < 8; ++Nt) {
                int n = wn*128 + Nt*16 + lr;
                s16x8 bf = *(const s16x8*)&wT[p*65536 + n*256 + ks*32 + lg*8];
#pragma unroll
                for (int Mt = 0; Mt < 4; ++Mt)
                    acc[Mt][Nt] = mfma_bf16(af[Mt], bf, acc[Mt][Nt]);
            }
        }
#pragma unroll
        for (int Nt = 0; Nt < 8; ++Nt) {
            float bv = bias[wn*128 + Nt*16 + lr];
#pragma unroll
            for (int Mt = 0; Mt < 4; ++Mt)
#pragma unroll
                for (int q = 0; q < 4; ++q) acc[Mt][Nt][q] += bv;
        }

        if (p == 2) {
#pragma unroll
            for (int Mt = 0; Mt < 4; ++Mt)
#pragma unroll
                for (int Nt = 0; Nt < 8; ++Nt) {
                    int n = wn*128 + Nt*16 + lr;
                    int mrow = m0 + wm*64 + Mt*16 + lg*4;
                    int bb = mrow >> 12, pos = mrow & 4095;
                    uint2 val;
                    val.x = pk2(acc[Mt][Nt][0], acc[Mt][Nt][1]);
                    val.y = pk2(acc[Mt][Nt][2], acc[Mt][Nt][3]);
                    *(uint2*)(xw3T + ((size_t)(bb*256 + n)*4096 + pos)*2) = val;
                }
        } else {
            const int fi = (p < 2) ? p : p - 1;
#pragma unroll
            for (int Mt = 0; Mt < 4; ++Mt)
#pragma unroll
                for (int Nt = 0; Nt < 8; ++Nt) {
                    int n = wn*128 + Nt*16 + lr;
#pragma unroll
                    for (int q = 0; q < 4; ++q) {
                        int m = wm*64 + Mt*16 + lg*4 + q;
                        *(u16*)&sC[m*512 + ((n*2) ^ ((m & 7) << 4))] = f2bf(acc[Mt][Nt][q]);
                    }
                }
            __syncthreads();
            {
                const int m = t >> 1, h = t & 1;
                u8* dst = f8 + (size_t)fi * SZ_F8 + (size_t)(m0 + m)*256 + h*128;
#pragma unroll
                for (int c = 0; c < 16; ++c) {
                    uint4 v = *(const uint4*)&sC[m*512 + ((h*256 + c*16) ^ ((m & 7) << 4))];
                    float fv[8] = { bf2f((u16)(v.x & 0xffff)), bf2f((u16)(v.x >> 16)),
                                    bf2f((u16)(v.y & 0xffff)), bf2f((u16)(v.y >> 16)),
                                    bf2f((u16)(v.z & 0xffff)), bf2f((u16)(v.z >> 16)),
                                    bf2f((u16)(v.w & 0xffff)), bf2f((u16)(v.w >> 16)) };
                    u32 o0 = 0, o1 = 0;
                    o0 = __builtin_amdgcn_cvt_pk_fp8_f32(fv[0], fv[1], o0, false);
                    o0 = __builtin_amdgcn_cvt_pk_fp8_f32(fv[2], fv[3], o0, true);
                    o1 = __builtin_amdgcn_cvt_pk_fp8_f32(fv[4], fv[5], o1, false);
                    o1 = __builtin_amdgcn_cvt_pk_fp8_f32(fv[6], fv[7], o1, true);
                    uint2 ov; ov.x = o0; ov.y = o1;
                    *(uint2*)(dst + c*8) = ov;
                }
            }
            __syncthreads();
        }
    }
}

// ---------------------------------------------------------------------------
// score: Sx,Sg fp8 MFMA; writes E=exp(Sx)*exp(Sg) bf16 (nt stores) + Zx/Zg
// partials. j-tile 32. grid 256*nb, 256 thr.
// ---------------------------------------------------------------------------
__global__ __launch_bounds__(256, 3) void score_kernel(
    const u8* __restrict__ f8, float* __restrict__ ZxP, float* __restrict__ ZgP,
    u8* __restrict__ PT, int bbase, int big)
{
    const int sid = xcd_swz(blockIdx.x, gridDim.x);
    const int bz = sid >> 8, rem = sid & 255;
    const int batch = bbase + bz;
    const int iblk = rem & 31, js = rem >> 5;
    const int i0 = iblk * 128;
    const int t = threadIdx.x, l = t & 63, lr = l & 15, lg = l >> 4, w = t >> 6;
    const u8* Ax = f8 + SZ_F8*1 + ((size_t)(batch*NPOS + i0 + w*32))*256;
    const u8* Ag = f8 + SZ_F8*3 + ((size_t)(batch*NPOS + i0 + w*32))*256;
    const u8* Bx = f8 + SZ_F8*0 + ((size_t)(batch*NPOS))*256;
    const u8* Bg = f8 + SZ_F8*2 + ((size_t)(batch*NPOS))*256;
    u8* PTb = PT + (big ? (size_t)bz * PBYTES : 0);

    long ax[2][8], ag[2][8];
#pragma unroll
    for (int Mt = 0; Mt < 2; ++Mt)
#pragma unroll
        for (int ks = 0; ks < 8; ++ks) {
            ax[Mt][ks] = *(const long*)&Ax[(Mt*16 + lr)*256 + ks*32 + lg*8];
            ag[Mt][ks] = *(const long*)&Ag[(Mt*16 + lr)*256 + ks*32 + lg*8];
        }

    float zx[2][4], zg[2][4];
#pragma unroll
    for (int Mt = 0; Mt < 2; ++Mt)
#pragma unroll
        for (int q = 0; q < 4; ++q) { zx[Mt][q] = 0.f; zg[Mt][q] = 0.f; }

    __shared__ __attribute__((aligned(16))) u8 sb[16384];
    __shared__ __attribute__((aligned(16))) u8 pb[8192];   // [32 j][128 i] bf16
    for (int jc = 0; jc < 16; ++jc) {
        const int j0 = js*512 + jc*32;
#pragma unroll
        for (int rep = 0; rep < 4; ++rep) {
            int s = rep*256 + t;
            int br = s >> 9, s2 = s & 511;
            int jr = s2 >> 4, kb = (s2 & 15) << 4;
            const u8* src = (br ? Bg : Bx) + (size_t)(j0 + jr)*256 + kb;
            uint4 v = *(const uint4*)src;
            int a0 = br*8192 + jr*256 + (kb ^ ((jr & 15) << 3));
            *(u64*)&sb[a0]     = ((u64)v.y << 32) | v.x;
            *(u64*)&sb[a0 ^ 8] = ((u64)v.w << 32) | v.z;
        }
        __syncthreads();
        f32x4 cx[2][2], cg[2][2];
#pragma unroll
        for (int Mt = 0; Mt < 2; ++Mt)
#pragma unroll
            for (int jt = 0; jt < 2; ++jt) { cx[Mt][jt] = (f32x4){0,0,0,0}; cg[Mt][jt] = (f32x4){0,0,0,0}; }
#pragma unroll
        for (int ks = 0; ks < 8; ++ks)
#pragma unroll
            for (int jt = 0; jt < 2; ++jt) {
                int jrow = jt*16 + lr;
                int off = jrow*256 + ((ks*32 + lg*8) ^ ((jrow & 15) << 3));
                long bxv = *(const long*)&sb[off];
                long bgv = *(const long*)&sb[8192 + off];
#pragma unroll
                for (int Mt = 0; Mt < 2; ++Mt) {
                    cx[Mt][jt] = mfma_fp8(ax[Mt][ks], bxv, cx[Mt][jt]);
                    cg[Mt][jt] = mfma_fp8(ag[Mt][ks], bgv, cg[Mt][jt]);
                }
            }
        // E = exp(Sx)*exp(Sg) -> LDS bounce; Zx,Zg accumulate
#pragma unroll
        for (int Mt = 0; Mt < 2; ++Mt)
#pragma unroll
            for (int jt = 0; jt < 2; ++jt) {
                int jl = jt*16 + lr;
                float e[4];
#pragma unroll
                for (int q = 0; q < 4; ++q) {
                    float exv = __expf(cx[Mt][jt][q]);
                    float egv = __expf(cg[Mt][jt][q]);
                    zx[Mt][q] += exv;
                    zg[Mt][q] += egv;
                    e[q] = exv * egv;
                }
                u64 pk = (u64)pk2(e[0], e[1]) | ((u64)pk2(e[2], e[3]) << 32);
                int ioff = w*64 + Mt*32 + lg*8;
                *(u64*)&pb[jl*256 + (ioff ^ ((jl & 15) << 3))] = pk;
            }
        __syncthreads();
        { // coalesced E store (nt): 32 rows x 256 B
            const int row = t >> 3, seg = t & 7;
            const int swz = (row & 15) << 3;
            u8* dst = PTb + (size_t)(j0 + row)*8192 + (size_t)i0*2 + seg*32;
#pragma unroll
            for (int h = 0; h < 2; ++h) {
                int a0 = row*256 + ((seg*32 + h*16) ^ swz);
                u64 lo = *(const u64*)&pb[a0];
                u64 hi = *(const u64*)&pb[a0 ^ 8];
                u32x4 o;
                o[0] = (u32)lo; o[1] = (u32)(lo >> 32);
                o[2] = (u32)hi; o[3] = (u32)(hi >> 32);
                ntst(dst + h*16, o);
            }
        }
        __syncthreads();
    }
#pragma unroll
    for (int Mt = 0; Mt < 2; ++Mt)
#pragma unroll
        for (int q = 0; q < 4; ++q)
#pragma unroll
            for (int o = 1; o < 16; o <<= 1) {
                zx[Mt][q] += __shfl_xor(zx[Mt][q], o, 64);
                zg[Mt][q] += __shfl_xor(zg[Mt][q], o, 64);
            }
    if (lr == 0) {
#pragma unroll
        for (int Mt = 0; Mt < 2; ++Mt)
#pragma unroll
            for (int q = 0; q < 4; ++q) {
                int gi = batch*NPOS + i0 + w*32 + Mt*16 + lg*4 + q;
                ZxP[js*MTOT + gi] = zx[Mt][q];
                ZgP[js*MTOT + gi] = zg[Mt][q];
            }
    }
}

// ---------------------------------------------------------------------------
__global__ __launch_bounds__(256) void merge_d(
    const float* __restrict__ ZxP, const float* __restrict__ ZgP,
    float* __restrict__ iD, int bbase)
{
    int gi = bbase*NPOS + blockIdx.x*256 + threadIdx.x;
    float zx = 0.f, zg = 0.f;
#pragma unroll
    for (int js = 0; js < 8; ++js) { zx += ZxP[js*MTOT + gi]; zg += ZgP[js*MTOT + gi]; }
    iD[gi] = 1.0f / (zx * zg);
}

// ---------------------------------------------------------------------------
// zpass: in-place E -> P = exp(E*iD) (bf16, nt) + z2 partials.
// ---------------------------------------------------------------------------
__global__ __launch_bounds__(256) void zpass_kernel(
    u8* __restrict__ PT, const float* __restrict__ iD,
    float* __restrict__ z2P, int bbase, int big)
{
    const int sid = xcd_swz(blockIdx.x, gridDim.x);
    const int bz = sid >> 7, r = sid & 127;
    const int ih = r >> 6, js = r & 63;
    const int batch = bbase + bz;
    u8* base = PT + (big ? (size_t)bz * PBYTES : 0) + (size_t)(js*64)*8192;
    const int i = ih*2048 + threadIdx.x*8;
    f32x4 d0 = *(const f32x4*)&iD[batch*NPOS + i];
    f32x4 d1 = *(const f32x4*)&iD[batch*NPOS + i + 4];
    f32x4 z0 = (f32x4){0,0,0,0}, z1 = (f32x4){0,0,0,0};
#pragma unroll 4
    for (int jr = 0; jr < 64; ++jr) {
        u8* addr = base + (size_t)jr*8192 + (size_t)i*2;
        u32x4 v = ntld(addr);
        float p0 = __expf(bf2f((u16)(v[0] & 0xffff)) * d0[0]);
        float p1 = __expf(bf2f((u16)(v[0] >> 16))    * d0[1]);
        float p2 = __expf(bf2f((u16)(v[1] & 0xffff)) * d0[2]);
        float p3 = __expf(bf2f((u16)(v[1] >> 16))    * d0[3]);
        float p4 = __expf(bf2f((u16)(v[2] & 0xffff)) * d1[0]);
        float p5 = __expf(bf2f((u16)(v[2] >> 16))    * d1[1]);
        float p6 = __expf(bf2f((u16)(v[3] & 0xffff)) * d1[2]);
        float p7 = __expf(bf2f((u16)(v[3] >> 16))    * d1[3]);
        z0[0] += p0; z0[1] += p1; z0[2] += p2; z0[3] += p3;
        z1[0] += p4; z1[1] += p5; z1[2] += p6; z1[3] += p7;
        u32x4 o;
        o[0] = pk2(p0, p1); o[1] = pk2(p2, p3);
        o[2] = pk2(p4, p5); o[3] = pk2(p6, p7);
        ntst(addr, o);
    }
    float* dst = z2P + (size_t)js*MTOT + batch*NPOS + i;
    *(f32x4*)dst = z0;
    *(f32x4*)(dst + 4) = z1;
}

// ---------------------------------------------------------------------------
__global__ __launch_bounds__(256) void prep_iz2(
    const float* __restrict__ z2P, float* __restrict__ iZ2, int bbase)
{
    int gi = bbase*NPOS + blockIdx.x*256 + threadIdx.x;
    float s = 0.f;
#pragma unroll 8
    for (int js = 0; js < 64; ++js) s += z2P[js*MTOT + gi];
    iZ2[gi] = 1.0f / s;
}

// ---------------------------------------------------------------------------
// scalev_ip: xw3T[b][c][i] *= iZ2[b][i], in place.
// ---------------------------------------------------------------------------
__global__ __launch_bounds__(256) void scalev_ip(
    u8* __restrict__ xw3T, const float* __restrict__ iZ2, int bbase)
{
    int eg = blockIdx.x*256 + threadIdx.x;
    int bz = bbase + (eg >> 17);
    int rem = eg & 131071;
    int c = rem >> 9, i = (rem & 511) << 3;
    size_t off = ((size_t)(bz*256 + c)*4096 + i)*2;
    uint4 v = *(const uint4*)(xw3T + off);
    f32x4 z0 = *(const f32x4*)&iZ2[bz*NPOS + i];
    f32x4 z1 = *(const f32x4*)&iZ2[bz*NPOS + i + 4];
    uint4 r;
    r.x = pk2(bf2f((u16)(v.x & 0xffff))*z0[0], bf2f((u16)(v.x >> 16))*z0[1]);
    r.y = pk2(bf2f((u16)(v.y & 0xffff))*z0[2], bf2f((u16)(v.y >> 16))*z0[3]);
    r.z = pk2(bf2f((u16)(v.z & 0xffff))*z1[0], bf2f((u16)(v.z >> 16))*z1[1]);
    r.w = pk2(bf2f((u16)(v.w & 0xffff))*z1[2], bf2f((u16)(v.w >> 16))*z1[3]);
    *(uint4*)(xw3T + off) = r;
}

// ---------------------------------------------------------------------------
// pv: out = x + P @ xw3s^T. Pure bf16 GEMM, double-buffered reg-staged LDS,
// one barrier per K-step. Tile 64j x 64c, K-step 64, grid 256*nb.
// c is the FAST sid index (L2 sharing of P panels); cached loads.
// ---------------------------------------------------------------------------
__global__ __launch_bounds__(256, 4) void pv_kernel(
    const u8* __restrict__ PT, const u8* __restrict__ xw3T,
    const float* __restrict__ x, float* __restrict__ out, int bbase, int big)
{
    const int sid = xcd_swz(blockIdx.x, gridDim.x);
    const int bz = sid >> 8, rem = sid & 255;
    const int batch = bbase + bz;
    const int j0 = (rem >> 2) * 64, c0 = (rem & 3) * 64;
    const u8* PTb = PT + (big ? (size_t)bz * PBYTES : 0);
    const u8* xw3Tb = xw3T + (size_t)batch * 256 * 4096 * 2;
    __shared__ __attribute__((aligned(16))) u8 sA[2][8192];   // bf16 [64 j][64 k]
    __shared__ __attribute__((aligned(16))) u8 sB[2][8192];   // bf16 [64 c][64 k]
    const int t = threadIdx.x, l = t & 63, lr = l & 15, lg = l >> 4;
    const int wv = t >> 6, wm = wv >> 1, wn = wv & 1;
    const int srow = t >> 3, sseg = t & 7;

    f32x4 acc[2][2];
#pragma unroll
    for (int Mt = 0; Mt < 2; ++Mt)
#pragma unroll
        for (int Nt = 0; Nt < 2; ++Nt) acc[Mt][Nt] = (f32x4){0,0,0,0};

    u32x4 ra[2], rb[2];
    {   // prologue: load tile 0
#pragma unroll
        for (int rp = 0; rp < 2; ++rp) {
            int row = rp*32 + srow;
            ra[rp] = *(const u32x4*)(PTb + (size_t)(j0 + row)*8192 + (size_t)(sseg*8)*2);
            rb[rp] = *(const u32x4*)(xw3Tb + ((size_t)(c0 + row)*4096 + sseg*8)*2);
        }
    }
    for (int kt = 0; kt < 64; ++kt) {
        const int cur = kt & 1;
#pragma unroll
        for (int rp = 0; rp < 2; ++rp) {
            int row = rp*32 + srow;
            int ad = row*128 + ((sseg*16) ^ ((row & 7) << 4));
            *(u32x4*)&sA[cur][ad] = ra[rp];
            *(u32x4*)&sB[cur][ad] = rb[rp];
        }
        __syncthreads();
        if (kt < 63) {   // issue next tile's loads; latency hides under MFMA
            const int k0 = (kt + 1) * 64;
#pragma unroll
            for (int rp = 0; rp < 2; ++rp) {
                int row = rp*32 + srow;
                ra[rp] = *(const u32x4*)(PTb + (size_t)(j0 + row)*8192 + (size_t)(k0 + sseg*8)*2);
                rb[rp] = *(const u32x4*)(xw3Tb + ((size_t)(c0 + row)*4096 + k0 + sseg*8)*2);
            }
        }
#pragma unroll
        for (int ks = 0; ks < 2; ++ks) {
            s16x8 af[2], bf[2];
#pragma unroll
            for (int Mt = 0; Mt < 2; ++Mt) {
                int row = wm*32 + Mt*16 + lr;
                af[Mt] = *(const s16x8*)&sA[cur][row*128 + ((ks*64 + lg*16) ^ ((row & 7) << 4))];
            }
#pragma unroll
            for (int Nt = 0; Nt < 2; ++Nt) {
                int row = wn*32 + Nt*16 + lr;
                bf[Nt] = *(const s16x8*)&sB[cur][row*128 + ((ks*64 + lg*16) ^ ((row & 7) << 4))];
            }
#pragma unroll
            for (int Mt = 0; Mt < 2; ++Mt)
#pragma unroll
                for (int Nt = 0; Nt < 2; ++Nt)
                    acc[Mt][Nt] = mfma_bf16(af[Mt], bf[Nt], acc[Mt][Nt]);
        }
    }
#pragma unroll
    for (int Mt = 0; Mt < 2; ++Mt)
#pragma unroll
        for (int Nt = 0; Nt < 2; ++Nt)
#pragma unroll
            for (int q = 0; q < 4; ++q) {
                int j = j0 + wm*32 + Mt*16 + lg*4 + q;
                int c = c0 + wn*32 + Nt*16 + lr;
                size_t idx = ((size_t)(batch*NPOS + j))*256 + c;
                out[idx] = x[idx] + acc[Mt][Nt][q];
            }
}

// ---------------------------------------------------------------------------
extern "C" void kernel_launch(void* const* d_in, const int* in_sizes, int n_in,
                              void* d_out, int out_size, void* d_ws, size_t ws_size,
                              hipStream_t stream)
{
    const float* x = (const float*)d_in[0];
    const float* g = (const float*)d_in[1];
    const float* W[5]  = {(const float*)d_in[2], (const float*)d_in[4], (const float*)d_in[6],
                          (const float*)d_in[8], (const float*)d_in[10]};
    const float* Bi[5] = {(const float*)d_in[3], (const float*)d_in[5], (const float*)d_in[7],
                          (const float*)d_in[9], (const float*)d_in[11]};
    char* ws = (char*)d_ws;
    u8*  f8   = (u8*)(ws + O_F8);
    u16* wT   = (u16*)(ws + O_WT);
    u8*  xw3T = (u8*)(ws + O_XW3T);
    float* ZxP = (float*)(ws + O_ZX);
    float* ZgP = (float*)(ws + O_ZG);
    float* iD  = (float*)(ws + O_ID);
    float* z2P = (float*)(ws + O_Z2);
    float* iZ2 = (float*)(ws + O_IZ2);
    u8*  PT   = (u8*)(ws + O_P);
    float* out = (float*)d_out;

    const int big = (ws_size >= O_P + 4 * PBYTES) ? 1 : 0;

    prep_w<<<dim3(5,4), 256, 0, stream>>>(W[0], W[1], W[2], W[3], W[4], (u32*)wT);
    proj_kernel<<<dim3(128,2), 256, 0, stream>>>(x, g, Bi[0], Bi[1], Bi[2], Bi[3], Bi[4],
                                                 wT, f8, xw3T);
    if (big) {
        score_kernel<<<1024, 256, 0, stream>>>(f8, ZxP, ZgP, PT, 0, 1);
        merge_d<<<64, 256, 0, stream>>>(ZxP, ZgP, iD, 0);
        zpass_kernel<<<512, 256, 0, stream>>>(PT, iD, z2P, 0, 1);
        prep_iz2<<<64, 256, 0, stream>>>(z2P, iZ2, 0);
        scalev_ip<<<2048, 256, 0, stream>>>(xw3T, iZ2, 0);
        pv_kernel<<<1024, 256, 0, stream>>>(PT, xw3T, x, out, 0, 1);
    } else {
        for (int b = 0; b < 4; ++b) {
            score_kernel<<<256, 256, 0, stream>>>(f8, ZxP, ZgP, PT, b, 0);
            merge_d<<<16, 256, 0, stream>>>(ZxP, ZgP, iD, b);
            zpass_kernel<<<128, 256, 0, stream>>>(PT, iD, z2P, b, 0);
            prep_iz2<<<16, 256, 0, stream>>>(z2P, iZ2, b);
            scalev_ip<<<512, 256, 0, stream>>>(xw3T, iZ2, b);
            pv_kernel<<<256, 256, 0, stream>>>(PT, xw3T, x, out, b, 0);
        }
    }
}